// Round 8
// baseline (1526.379 us; speedup 1.0000x reference)
//
#include <hip/hip_runtime.h>
#include <hip/hip_bf16.h>

typedef __hip_bfloat16 bf16;
typedef __attribute__((ext_vector_type(8))) short bf16x8;   // 8 bf16 = 4 VGPRs (MFMA A/B frag)
typedef __attribute__((ext_vector_type(4))) float f32x4;    // MFMA C/D frag

#define NT   37824   // total tokens = 192*197
#define MPAD 37888   // 148*256 (padded rows for 256-tile GEMM)
#define EDIM 768
#define N3   2304
#define TP   197     // tokens per frame
#define NB   16
#define NF   12
#define NH   12
#define HD   64
#define SCALE 0.125f
#define KALL 2364    // 12*197

__device__ __forceinline__ float bits2f(unsigned short u) {
    unsigned int v = ((unsigned int)u) << 16;
    return __uint_as_float(v);
}
__device__ __forceinline__ float b2f(bf16 v) { return __bfloat162float(v); }

__device__ __forceinline__ unsigned short bhi(float x) {
    union { bf16 b; unsigned short u; } cv; cv.b = __float2bfloat16(x); return cv.u;
}
__device__ __forceinline__ unsigned short blo(float x, unsigned short h) {
    float hf = __uint_as_float(((unsigned int)h) << 16);
    union { bf16 b; unsigned short u; } cv; cv.b = __float2bfloat16(x - hf); return cv.u;
}

__device__ __forceinline__ void storeC(float* p, float v) { *p = v; }
__device__ __forceinline__ void storeC(bf16* p, float v) { *p = __float2bfloat16(v); }

// async global->LDS, 16B per lane; lds dest = wave-uniform base + lane*16
__device__ __forceinline__ void gload_lds16(const bf16* g, bf16* l) {
    __builtin_amdgcn_global_load_lds(
        (const __attribute__((address_space(1))) void*)g,
        (__attribute__((address_space(3))) void*)l,
        16, 0, 0);
}

// ---------------- K1: mid = x @ lora_a^T  (NT x 8), fp32 in ----------------
__global__ __launch_bounds__(256) void lora_mid_kernel(const float* __restrict__ x,
        const float* __restrict__ la, float* __restrict__ mid) {
    int t = blockIdx.x * 4 + (threadIdx.x >> 6);
    int lane = threadIdx.x & 63;
    if (t >= NT) return;
    float acc[8];
#pragma unroll
    for (int r = 0; r < 8; r++) acc[r] = 0.f;
    const float* xr = x + (size_t)t * EDIM;
    for (int e = lane; e < EDIM; e += 64) {
        float xv = xr[e];
#pragma unroll
        for (int r = 0; r < 8; r++) acc[r] += xv * la[r * EDIM + e];
    }
#pragma unroll
    for (int r = 0; r < 8; r++) {
        float v = acc[r];
#pragma unroll
        for (int off = 32; off >= 1; off >>= 1) v += __shfl_xor(v, off, 64);
        if (lane == 0) mid[(size_t)t * 8 + r] = v;
    }
}

// ---- split fp32 rows x 768 -> bf16 [hi | lo] rows x 1536 (used for W and for x) --------
__global__ __launch_bounds__(256) void split_w_kernel(const float* __restrict__ w,
        bf16* __restrict__ o, int rows) {
    int idx = blockIdx.x * 256 + threadIdx.x;
    int total = rows * 192;                        // 768/4 float4-chunks per row
    if (idx >= total) return;
    int r = idx / 192, c = (idx - r * 192) * 4;
    float4 v = *reinterpret_cast<const float4*>(w + (size_t)r * 768 + c);
    ushort4 hi, lo;
    hi.x = bhi(v.x); hi.y = bhi(v.y); hi.z = bhi(v.z); hi.w = bhi(v.w);
    lo.x = blo(v.x, hi.x); lo.y = blo(v.y, hi.y); lo.z = blo(v.z, hi.z); lo.w = blo(v.w, hi.w);
    *(ushort4*)(o + (size_t)r * 1536 + c) = hi;
    *(ushort4*)(o + (size_t)r * 1536 + 768 + c) = lo;
}

// ---------------- MFMA GEMM, 256x256 tile, phase-barrier counted-vmcnt pipeline ---------
// Virtual-K decomposition (fp32 accuracy from bf16 MFMA):
//   QKV  (KV=2304, A = xs [x_hi | x_lo], lda=1536): x_hi@Whi + x_hi@Wlo + x_lo@Whi
//   proj (KV=1536, A = ao,               lda=768 ): ao@Whi + ao@Wlo
// 8 waves (2M x 4N), per-wave output 128x64, BK=64; LDS = 128 KiB (2x dbuf).
// K-loop = 4 PHASES with m201's barrier discipline (the role-split that makes
// setprio pay, m218b; absent in r6/r7's barrier-free clusters):
//   P1: read a(mh0)+b0 | bar | lgkmcnt(0) | prio1 16 MFMA prio0 | bar
//   P2: read b1        | bar | lgkmcnt(0) | prio1 16 MFMA prio0 | bar
//   P3: read a(mh1)    | bar | lgkmcnt(0) | prio1 16 MFMA prio0 | bar
//       (buf[cur] dead for all waves after P3's trailing barrier)
//   STAGE tile t+2 into freed buf; sched_barrier
//   P4: prio1 16 MFMA (registers only) prio0   <- overlaps t+2's load flight
//   vmcnt(8) counted (waits t+1 only, t+2 in flight); bar; cur^=1
// 7 unconditional barriers/tile, wave-uniform -> no deadlock. lgkmcnt(0) asm is
// followed by sched_barrier(0) (rule #18). Swizzle: LDS byte^=((row&7)<<4) via
// inverse-swizzled global source (rule #21). 0 bank conflicts verified r2-r7.
template <typename OT, bool LORA>
__global__ __launch_bounds__(512, 2) void mfma_gemm_kernel(const bf16* __restrict__ A, int lda,
        const bf16* __restrict__ W, const float* __restrict__ bias,
        const float* __restrict__ mid, const float* __restrict__ lb,
        OT* __restrict__ C, int M, int N, int KV) {
    __shared__ bf16 As[2][256 * 64];
    __shared__ bf16 Bs[2][256 * 64];
    const int tid = threadIdx.x;
    const int w = tid >> 6, lane = tid & 63;
    const int lr = lane & 15, lg = lane >> 4;
    const int wr = w >> 2, wc = w & 3;          // 2M x 4N wave grid

    // bijective XCD-chunk swizzle (general form, m204)
    const int gx = gridDim.x;
    const int nwg = gx * gridDim.y;
    const int flat = blockIdx.y * gx + blockIdx.x;
    const int xcd = flat & 7, loc = flat >> 3;
    const int q = nwg >> 3, rmd = nwg & 7;
    const int lid = (xcd < rmd ? xcd * (q + 1) : rmd * (q + 1) + (xcd - rmd) * q) + loc;
    const int m0 = (lid / gx) * 256, n0 = (lid % gx) * 256;

    f32x4 acc[8][4];
#pragma unroll
    for (int i = 0; i < 8; i++)
#pragma unroll
        for (int j = 0; j < 4; j++) acc[i][j] = (f32x4){0.f, 0.f, 0.f, 0.f};

    // staging source swizzle (rule #21)
    const int brs = lane >> 3;
    const int bcsw = ((lane & 7) ^ brs) << 3;

    // wave w stages rows w*32 .. w*32+31 of both A and B tiles (4 x 1KB segs each)
    auto STAGE = [&](bf16* dA, bf16* dB, int aO, int wO) {
#pragma unroll
        for (int j = 0; j < 4; ++j) {
            int rA = w * 32 + j * 8;
            gload_lds16(A + (size_t)(m0 + rA + brs) * lda + aO + bcsw, dA + rA * 64);
            gload_lds16(W + (size_t)(n0 + rA + brs) * 1536 + wO + bcsw, dB + rA * 64);
        }
    };

    const int nt = KV / 64;
    // ---- prologue: stage tiles 0,1; wait tile 0 (tile 1's 8 stay in flight) ----
    STAGE(&As[0][0], &Bs[0][0], 0, 0);
    {
        const int k1 = 64;
        STAGE(&As[1][0], &Bs[1][0], (k1 >= 768) ? k1 - 768 : k1, k1);
    }
    asm volatile("s_waitcnt vmcnt(8)" ::: "memory");
    __builtin_amdgcn_sched_barrier(0);
    __builtin_amdgcn_s_barrier();
    __builtin_amdgcn_sched_barrier(0);

    int cur = 0;
    for (int t = 0; t < nt; ++t) {
        const char* pA = (const char*)&As[cur][0];
        const char* pB = (const char*)&Bs[cur][0];
        bf16x8 a[4][2], b0[2][2], b1[2][2];
        // ======== phase 1: read a(m-half0)+b0; 16 MFMA ========
#pragma unroll
        for (int mf = 0; mf < 4; mf++) {
            int row = wr * 128 + mf * 16 + lr;
            int sw = (row & 7) << 4;
            a[mf][0] = *(const bf16x8*)(pA + row * 128 + ((lg * 16) ^ sw));
            a[mf][1] = *(const bf16x8*)(pA + row * 128 + ((64 + lg * 16) ^ sw));
        }
#pragma unroll
        for (int nf = 0; nf < 2; nf++) {
            int row = wc * 64 + nf * 16 + lr;
            int sw = (row & 7) << 4;
            b0[nf][0] = *(const bf16x8*)(pB + row * 128 + ((lg * 16) ^ sw));
            b0[nf][1] = *(const bf16x8*)(pB + row * 128 + ((64 + lg * 16) ^ sw));
        }
        __builtin_amdgcn_sched_barrier(0);
        __builtin_amdgcn_s_barrier();
        asm volatile("s_waitcnt lgkmcnt(0)" ::: "memory");
        __builtin_amdgcn_sched_barrier(0);
        __builtin_amdgcn_s_setprio(1);
#pragma unroll
        for (int mf = 0; mf < 4; mf++)
#pragma unroll
            for (int nf = 0; nf < 2; nf++) {
                acc[mf][nf] = __builtin_amdgcn_mfma_f32_16x16x32_bf16(a[mf][0], b0[nf][0], acc[mf][nf], 0, 0, 0);
                acc[mf][nf] = __builtin_amdgcn_mfma_f32_16x16x32_bf16(a[mf][1], b0[nf][1], acc[mf][nf], 0, 0, 0);
            }
        __builtin_amdgcn_s_setprio(0);
        __builtin_amdgcn_sched_barrier(0);
        __builtin_amdgcn_s_barrier();
        __builtin_amdgcn_sched_barrier(0);
        // ======== phase 2: read b1; 16 MFMA ========
#pragma unroll
        for (int nf = 0; nf < 2; nf++) {
            int row = wc * 64 + (nf + 2) * 16 + lr;
            int sw = (row & 7) << 4;
            b1[nf][0] = *(const bf16x8*)(pB + row * 128 + ((lg * 16) ^ sw));
            b1[nf][1] = *(const bf16x8*)(pB + row * 128 + ((64 + lg * 16) ^ sw));
        }
        __builtin_amdgcn_sched_barrier(0);
        __builtin_amdgcn_s_barrier();
        asm volatile("s_waitcnt lgkmcnt(0)" ::: "memory");
        __builtin_amdgcn_sched_barrier(0);
        __builtin_amdgcn_s_setprio(1);
#pragma unroll
        for (int mf = 0; mf < 4; mf++)
#pragma unroll
            for (int nf = 0; nf < 2; nf++) {
                acc[mf][nf + 2] = __builtin_amdgcn_mfma_f32_16x16x32_bf16(a[mf][0], b1[nf][0], acc[mf][nf + 2], 0, 0, 0);
                acc[mf][nf + 2] = __builtin_amdgcn_mfma_f32_16x16x32_bf16(a[mf][1], b1[nf][1], acc[mf][nf + 2], 0, 0, 0);
            }
        __builtin_amdgcn_s_setprio(0);
        __builtin_amdgcn_sched_barrier(0);
        __builtin_amdgcn_s_barrier();
        __builtin_amdgcn_sched_barrier(0);
        // ======== phase 3: read a(m-half1) (WAR on a[]); 16 MFMA (a*b1) ========
#pragma unroll
        for (int mf = 0; mf < 4; mf++) {
            int row = wr * 128 + 64 + mf * 16 + lr;
            int sw = (row & 7) << 4;
            a[mf][0] = *(const bf16x8*)(pA + row * 128 + ((lg * 16) ^ sw));
            a[mf][1] = *(const bf16x8*)(pA + row * 128 + ((64 + lg * 16) ^ sw));
        }
        __builtin_amdgcn_sched_barrier(0);
        __builtin_amdgcn_s_barrier();
        asm volatile("s_waitcnt lgkmcnt(0)" ::: "memory");
        __builtin_amdgcn_sched_barrier(0);
        __builtin_amdgcn_s_setprio(1);
#pragma unroll
        for (int mf = 0; mf < 4; mf++)
#pragma unroll
            for (int nf = 0; nf < 2; nf++) {
                acc[4 + mf][nf + 2] = __builtin_amdgcn_mfma_f32_16x16x32_bf16(a[mf][0], b1[nf][0], acc[4 + mf][nf + 2], 0, 0, 0);
                acc[4 + mf][nf + 2] = __builtin_amdgcn_mfma_f32_16x16x32_bf16(a[mf][1], b1[nf][1], acc[4 + mf][nf + 2], 0, 0, 0);
            }
        __builtin_amdgcn_s_setprio(0);
        __builtin_amdgcn_sched_barrier(0);
        __builtin_amdgcn_s_barrier();            // buf[cur] dead for all waves
        __builtin_amdgcn_sched_barrier(0);
        // ---- stage tile t+2 into the freed buffer (overlaps phase 4) ----
        if (t + 2 < nt) {
            const int k2 = (t + 2) * 64;
            STAGE(&As[cur][0], &Bs[cur][0],
                  (k2 >= 768) ? k2 - 768 : k2,
                  (k2 >= 1536) ? k2 - 1536 : k2);
        }
        __builtin_amdgcn_sched_barrier(0);   // keep P4's MFMAs after the stage issue
        // ======== phase 4: 16 MFMA (a(mh1)*b0) — registers only ========
        __builtin_amdgcn_s_setprio(1);
#pragma unroll
        for (int mf = 0; mf < 4; mf++)
#pragma unroll
            for (int nf = 0; nf < 2; nf++) {
                acc[4 + mf][nf] = __builtin_amdgcn_mfma_f32_16x16x32_bf16(a[mf][0], b0[nf][0], acc[4 + mf][nf], 0, 0, 0);
                acc[4 + mf][nf] = __builtin_amdgcn_mfma_f32_16x16x32_bf16(a[mf][1], b0[nf][1], acc[4 + mf][nf], 0, 0, 0);
            }
        __builtin_amdgcn_s_setprio(0);
        // ---- counted wait for tile t+1 (t+2's 8 loads stay in flight) ----
        if (t + 2 < nt) {
            asm volatile("s_waitcnt vmcnt(8)" ::: "memory");
        } else {
            asm volatile("s_waitcnt vmcnt(0)" ::: "memory");
        }
        __builtin_amdgcn_sched_barrier(0);
        __builtin_amdgcn_s_barrier();            // t+1's LDS writes visible to all
        __builtin_amdgcn_sched_barrier(0);
        cur ^= 1;
    }
    // ---- epilogue: bias (+ LoRA), store ----
#pragma unroll
    for (int mf = 0; mf < 8; mf++) {
#pragma unroll
        for (int r = 0; r < 4; r++) {
            int m = m0 + wr * 128 + mf * 16 + lg * 4 + r;
            if (m < M) {
                float mr[8];
                if constexpr (LORA) {
                    float4 u0 = *reinterpret_cast<const float4*>(mid + (size_t)m * 8);
                    float4 u1 = *reinterpret_cast<const float4*>(mid + (size_t)m * 8 + 4);
                    mr[0] = u0.x; mr[1] = u0.y; mr[2] = u0.z; mr[3] = u0.w;
                    mr[4] = u1.x; mr[5] = u1.y; mr[6] = u1.z; mr[7] = u1.w;
                }
#pragma unroll
                for (int nf = 0; nf < 4; nf++) {
                    int n = n0 + wc * 64 + nf * 16 + lr;
                    float v = acc[mf][nf][r] + bias[n];
                    if constexpr (LORA) {
                        const float4 l0 = *reinterpret_cast<const float4*>(lb + (size_t)n * 8);
                        const float4 l1 = *reinterpret_cast<const float4*>(lb + (size_t)n * 8 + 4);
                        v += mr[0] * l0.x + mr[1] * l0.y + mr[2] * l0.z + mr[3] * l0.w
                           + mr[4] * l1.x + mr[5] * l1.y + mr[6] * l1.z + mr[7] * l1.w;
                    }
                    storeC(C + (size_t)m * N + n, v);
                }
            }
        }
    }
}

// ---------------- Fused per-frame attention, MFMA version ----------------
__global__ __launch_bounds__(256) void attn_kernel(const bf16* __restrict__ qkv,
        bf16* __restrict__ ao) {
    __shared__ bf16 Ks[208 * 64];      // [row][64]
    __shared__ bf16 Vt[64 * 208];      // [d][kk]
    __shared__ bf16 Ps[4][16 * 208];   // per-wave [q][kk]
    const int bb = blockIdx.x / NH;
    const int h = blockIdx.x % NH;
    const bf16* base = qkv + (size_t)bb * TP * N3;
    const int tid = threadIdx.x;
    const int w = tid >> 6, lane = tid & 63;
    const int lr = lane & 15, lg = lane >> 4;

    for (int idx = tid; idx < 208 * 16; idx += 256) {
        int row = idx >> 4, d4 = (idx & 15) * 4;
        ushort4 v = make_ushort4(0, 0, 0, 0);
        if (row < TP)
            v = *(const ushort4*)(base + (size_t)row * N3 + EDIM + h * 64 + d4);
        *(ushort4*)((char*)Ks + ((row * 128 + d4 * 2) ^ ((row & 7) << 4))) = v;
    }
    for (int g = w; g < 52; g += 4) {
        int kk0 = g * 4;
        int d = lane;
        const bf16* vb = base + (size_t)kk0 * N3 + 2 * EDIM + h * 64 + d;
        unsigned short t0 = 0, t1 = 0, t2 = 0, t3 = 0;
        if (kk0 + 0 < TP) t0 = *(const unsigned short*)(vb);
        if (kk0 + 1 < TP) t1 = *(const unsigned short*)(vb + N3);
        if (kk0 + 2 < TP) t2 = *(const unsigned short*)(vb + 2 * N3);
        if (kk0 + 3 < TP) t3 = *(const unsigned short*)(vb + 3 * N3);
        ushort4 v; v.x = t0; v.y = t1; v.z = t2; v.w = t3;
        *(ushort4*)((char*)Vt + ((d * 416 + kk0 * 2) ^ ((d & 7) << 4))) = v;
    }
    __syncthreads();

    bf16* Pw = &Ps[w][0];

    for (int qt = w; qt < 13; qt += 4) {
        int q = qt * 16 + lr; if (q > TP - 1) q = TP - 1;
        const bf16* qp = base + (size_t)q * N3 + h * 64 + lg * 8;
        bf16x8 qa0 = *(const bf16x8*)qp;
        bf16x8 qa1 = *(const bf16x8*)(qp + 32);

        f32x4 sf[13];
#pragma unroll
        for (int f = 0; f < 13; f++) {
            int row = f * 16 + lr;
            int swz = (row & 7) << 4;
            bf16x8 kb0 = *(const bf16x8*)((const char*)Ks + ((row * 128 + lg * 16) ^ swz));
            bf16x8 kb1 = *(const bf16x8*)((const char*)Ks + ((row * 128 + 64 + lg * 16) ^ swz));
            f32x4 c = {0.f, 0.f, 0.f, 0.f};
            c = __builtin_amdgcn_mfma_f32_16x16x32_bf16(qa0, kb0, c, 0, 0, 0);
            c = __builtin_amdgcn_mfma_f32_16x16x32_bf16(qa1, kb1, c, 0, 0, 0);
            sf[f] = c;
        }

        float mx[4] = {-1e30f, -1e30f, -1e30f, -1e30f};
#pragma unroll
        for (int f = 0; f < 13; f++) {
#pragma unroll
            for (int r = 0; r < 4; r++) {
                float s = sf[f][r] * SCALE;
                if (f == 12 && lr >= 5) s = -1e30f;
                sf[f][r] = s;
                mx[r] = fmaxf(mx[r], s);
            }
        }
#pragma unroll
        for (int off = 8; off >= 1; off >>= 1) {
#pragma unroll
            for (int r = 0; r < 4; r++) mx[r] = fmaxf(mx[r], __shfl_xor(mx[r], off, 64));
        }
        float lsum[4] = {0.f, 0.f, 0.f, 0.f};
#pragma unroll
        for (int f = 0; f < 13; f++) {
#pragma unroll
            for (int r = 0; r < 4; r++) {
                float e = __expf(sf[f][r] - mx[r]);
                sf[f][r] = e;
                lsum[r] += e;
            }
        }
#pragma unroll
        for (int off = 8; off >= 1; off >>= 1) {
#pragma unroll
            for (int r = 0; r < 4; r++) lsum[r] += __shfl_xor(lsum[r], off, 64);
        }
        float inv[4];
#pragma unroll
        for (int r = 0; r < 4; r++) inv[r] = 1.f / lsum[r];

#pragma unroll
        for (int f = 0; f < 13; f++) {
#pragma unroll
            for (int r = 0; r < 4; r++) {
                int row = lg * 4 + r;
                int col = f * 16 + lr;
                *(bf16*)((char*)Pw + ((row * 416 + col * 2) ^ ((row & 7) << 4))) =
                    __float2bfloat16(sf[f][r]);
            }
        }

        f32x4 of[4];
#pragma unroll
        for (int dt = 0; dt < 4; dt++) of[dt] = (f32x4){0.f, 0.f, 0.f, 0.f};
#pragma unroll
        for (int ks = 0; ks < 7; ks++) {
            int k0 = ks * 32 + lg * 8;
            bool ok = (k0 < 208);
            bf16x8 pa = {0, 0, 0, 0, 0, 0, 0, 0};
            if (ok)
                pa = *(const bf16x8*)((const char*)Pw + ((lr * 416 + k0 * 2) ^ ((lr & 7) << 4)));
#pragma unroll
            for (int dt = 0; dt < 4; dt++) {
                bf16x8 vb = {0, 0, 0, 0, 0, 0, 0, 0};
                if (ok) {
                    int d = dt * 16 + lr;
                    vb = *(const bf16x8*)((const char*)Vt + ((d * 416 + k0 * 2) ^ ((d & 7) << 4)));
                }
                of[dt] = __builtin_amdgcn_mfma_f32_16x16x32_bf16(pa, vb, of[dt], 0, 0, 0);
            }
        }

#pragma unroll
        for (int dt = 0; dt < 4; dt++) {
#pragma unroll
            for (int r = 0; r < 4; r++) {
                int qq = qt * 16 + lg * 4 + r;
                if (qq < TP)
                    ao[((size_t)bb * TP + qq) * EDIM + h * 64 + dt * 16 + lr] =
                        __float2bfloat16(of[dt][r] * inv[r]);
            }
        }
    }
}

// ---------------- Fused cross-frame CLS attention (flash-style online softmax) ----------
__global__ __launch_bounds__(256) void xattn_kernel(const bf16* __restrict__ qkv,
        float* __restrict__ x1p) {
    __shared__ float q1[NF][64];
    __shared__ bf16 Ks[128][64];
    __shared__ bf16 Vs[128][64];
    __shared__ float sc[NF][128];
    __shared__ float Oacc[NF][64];
    __shared__ float mrow[NF], lrow[NF], arow[NF];
    const int b = blockIdx.x / NH, h = blockIdx.x % NH;
    const int tid = threadIdx.x;
    for (int idx = tid; idx < NF * 64; idx += 256) {
        int f = idx >> 6, d = idx & 63;
        q1[f][d] = b2f(qkv[(size_t)((b * NF + f) * TP) * N3 + h * 64 + d]);
        Oacc[f][d] = 0.f;
    }
    if (tid < NF) { mrow[tid] = -1e30f; lrow[tid] = 0.f; }
    __syncthreads();
    const int w = tid >> 6, lane = tid & 63;
    for (int kk0 = 0; kk0 < KALL; kk0 += 128) {
        for (int idx = tid; idx < 128 * 16; idx += 256) {
            int r = idx >> 4, d4 = (idx & 15) * 4;
            int kk = kk0 + r;
            if (kk < KALL) {
                int f = kk / TP, pp = kk - f * TP;
                const bf16* src = qkv + (size_t)((b * NF + f) * TP + pp) * N3 + h * 64 + d4;
                *(ushort4*)&Ks[r][d4] = *(const ushort4*)(src + 768);
                *(ushort4*)&Vs[r][d4] = *(const ushort4*)(src + 1536);
            } else {
                ushort4 z; z.x = z.y = z.z = z.w = 0;
                *(ushort4*)&Ks[r][d4] = z;
                *(ushort4*)&Vs[r][d4] = z;
            }
        }
        __syncthreads();
        for (int idx = tid; idx < NF * 128; idx += 256) {
            int f = idx >> 7, r = idx & 127;
            float s = -1e30f;
            if (kk0 + r < KALL) {
                const bf16* kr = &Ks[r][0];
                float a = 0.f;
#pragma unroll
                for (int d2 = 0; d2 < 32; d2++) {
                    unsigned int u = *reinterpret_cast<const unsigned int*>(kr + 2 * d2);
                    a += q1[f][2 * d2] * __uint_as_float(u << 16);
                    a += q1[f][2 * d2 + 1] * __uint_as_float(u & 0xffff0000u);
                }
                s = a * SCALE;
            }
            sc[f][r] = s;
        }
        __syncthreads();
        for (int qi = 0; qi < 3; qi++) {
            int f = qi * 4 + w;
            float s0 = sc[f][lane], s1v = sc[f][lane + 64];
            float mx = fmaxf(s0, s1v);
#pragma unroll
            for (int off = 32; off >= 1; off >>= 1) mx = fmaxf(mx, __shfl_xor(mx, off, 64));
            float mold = mrow[f];
            float mnew = fmaxf(mold, mx);
            float e0 = __expf(s0 - mnew), e1 = __expf(s1v - mnew);
            float ls = e0 + e1;
#pragma unroll
            for (int off = 32; off >= 1; off >>= 1) ls += __shfl_xor(ls, off, 64);
            sc[f][lane] = e0; sc[f][lane + 64] = e1;
            if (lane == 0) {
                float alpha = __expf(mold - mnew);
                arow[f] = alpha;
                lrow[f] = lrow[f] * alpha + ls;
                mrow[f] = mnew;
            }
        }
        __syncthreads();
        for (int idx = tid; idx < NF * 64; idx += 256) {
            int f = idx >> 6, d = idx & 63;
            float o = Oacc[f][d] * arow[f];
#pragma unroll 4
            for (int r = 0; r < 128; r++)
                o += sc[f][r] * b2f(Vs[r][d]);
            Oacc[f][d] = o;
        }
        __syncthreads();
    }
    for (int idx = tid; idx < NF * 64; idx += 256) {
        int f = idx >> 6, d = idx & 63;
        x1p[(size_t)(b * NF + f) * EDIM + h * 64 + d] = Oacc[f][d] / lrow[f];
    }
}

// ---------------- CLS fixup: out[:,:,0,:] = MLP(out[:,:,0,:]) + x1p @ Wout^T + ob --------
__global__ __launch_bounds__(256) void cls_kernel(float* __restrict__ out,
        const float* __restrict__ x1p, const float* __restrict__ Wout, const float* __restrict__ ob,
        const float* __restrict__ dw, const float* __restrict__ db,
        const float* __restrict__ uw, const float* __restrict__ ub) {
    __shared__ float x0s[EDIM], x1s[EDIM], gs[8];
    const int bfi = blockIdx.x;
    float* row = out + (size_t)bfi * TP * EDIM;  // p = 0 row
    const int tid = threadIdx.x;
    for (int i = tid; i < EDIM; i += 256) {
        x0s[i] = row[i];
        x1s[i] = x1p[(size_t)bfi * EDIM + i];
    }
    __syncthreads();
    {
        int r = tid >> 5, sl = tid & 31;
        float pr = 0.f;
        for (int e = sl; e < EDIM; e += 32) pr += x0s[e] * dw[r * EDIM + e];
#pragma unroll
        for (int off = 16; off >= 1; off >>= 1) pr += __shfl_xor(pr, off, 64);
        if (sl == 0) gs[r] = pr + db[r];
    }
    __syncthreads();
    float act[8];
#pragma unroll
    for (int r = 0; r < 8; r++) { float g = gs[r]; act[r] = g / (1.f + __expf(-1.702f * g)); }
    for (int j = tid; j < EDIM; j += 256) {
        float y = ub[j] + ob[j];
        const float4 u0 = *reinterpret_cast<const float4*>(uw + (size_t)j * 8);
        const float4 u1 = *reinterpret_cast<const float4*>(uw + (size_t)j * 8 + 4);
        y += act[0] * u0.x + act[1] * u0.y + act[2] * u0.z + act[3] * u0.w
           + act[4] * u1.x + act[5] * u1.y + act[6] * u1.z + act[7] * u1.w;
        const float* wr = Wout + (size_t)j * EDIM;
        float s = 0.f;
        for (int e = 0; e < EDIM; e += 4) {
            float4 wv = *reinterpret_cast<const float4*>(wr + e);
            s += x1s[e] * wv.x + x1s[e + 1] * wv.y + x1s[e + 2] * wv.z + x1s[e + 3] * wv.w;
        }
        y += s;
        row[j] = y;
    }
}

extern "C" void kernel_launch(void* const* d_in, const int* in_sizes, int n_in,
                              void* d_out, int out_size, void* d_ws, size_t ws_size,
                              hipStream_t stream) {
    (void)in_sizes; (void)n_in; (void)out_size; (void)ws_size;
    const float* x   = (const float*)d_in[0];
    const float* ipw = (const float*)d_in[1];
    const float* ipb = (const float*)d_in[2];
    const float* opw = (const float*)d_in[3];
    const float* opb = (const float*)d_in[4];
    const float* la  = (const float*)d_in[5];
    const float* lb  = (const float*)d_in[6];
    const float* dw  = (const float*)d_in[7];
    const float* db  = (const float*)d_in[8];
    const float* uw  = (const float*)d_in[9];
    const float* ub  = (const float*)d_in[10];
    float* out = (float*)d_out;   // fp32 output per reference dtype

    // workspace: qkv 174.3 + ao 58.2 + xs 116.4 + W1 7.1 + W2 2.4 + mid 1.2 + x1p 0.6 ≈ 360 MB
    char* wsb = (char*)d_ws;
    bf16* qkv = (bf16*)wsb;                       wsb += (size_t)NT * N3 * sizeof(bf16);
    bf16* ao  = (bf16*)wsb;                       wsb += (size_t)MPAD * EDIM * sizeof(bf16);
    bf16* xs  = (bf16*)wsb;                       wsb += (size_t)MPAD * 1536 * sizeof(bf16);
    bf16* W1  = (bf16*)wsb;                       wsb += (size_t)N3 * 1536 * sizeof(bf16);
    bf16* W2  = (bf16*)wsb;                       wsb += (size_t)EDIM * 1536 * sizeof(bf16);
    float* mid = (float*)wsb;                     wsb += (size_t)NT * 8 * sizeof(float);
    float* x1p = (float*)wsb;                     wsb += (size_t)NB * NF * EDIM * sizeof(float);

    split_w_kernel<<<(N3 * 192 + 255) / 256, 256, 0, stream>>>(ipw, W1, N3);
    split_w_kernel<<<(EDIM * 192 + 255) / 256, 256, 0, stream>>>(opw, W2, EDIM);
    split_w_kernel<<<(NT * 192 + 255) / 256, 256, 0, stream>>>(x, xs, NT);
    lora_mid_kernel<<<NT / 4, 256, 0, stream>>>(x, la, mid);
    // QKV: virtual K = 2304 (hi*Whi + hi*Wlo + lo*Whi)
    mfma_gemm_kernel<bf16, true><<<dim3(N3 / 256, MPAD / 256), 512, 0, stream>>>(
        xs, 1536, W1, ipb, mid, lb, qkv, NT, N3, 2304);
    attn_kernel<<<192 * NH, 256, 0, stream>>>(qkv, ao);
    xattn_kernel<<<NB * NH, 256, 0, stream>>>(qkv, x1p);
    // out-proj: virtual K = 1536 (ao*Whi + ao*Wlo)
    mfma_gemm_kernel<float, false><<<dim3(EDIM / 256, MPAD / 256), 512, 0, stream>>>(
        ao, 768, W2, opb, nullptr, nullptr, out, NT, EDIM, 1536);
    cls_kernel<<<NB * NF, 256, 0, stream>>>(out, x1p, opw, opb, dw, db, uw, ub);
}

// Round 9
// 1265.753 us; speedup vs baseline: 1.2059x; 1.2059x over previous
//
#include <hip/hip_runtime.h>
#include <hip/hip_bf16.h>

typedef __hip_bfloat16 bf16;
typedef __attribute__((ext_vector_type(8))) short bf16x8;   // 8 bf16 = 4 VGPRs (MFMA A/B frag)
typedef __attribute__((ext_vector_type(4))) float f32x4;    // MFMA C/D frag

#define NT   37824   // total tokens = 192*197
#define MPAD 37888   // 148*256 (padded rows for 256-tile GEMM)
#define EDIM 768
#define N3   2304
#define TP   197     // tokens per frame
#define NB   16
#define NF   12
#define NH   12
#define HD   64
#define SCALE 0.125f
#define KALL 2364    // 12*197
#define NCH  4       // xattn KV-split chunks
#define KCH  591     // KALL / NCH

__device__ __forceinline__ float bits2f(unsigned short u) {
    unsigned int v = ((unsigned int)u) << 16;
    return __uint_as_float(v);
}
__device__ __forceinline__ float b2f(bf16 v) { return __bfloat162float(v); }

__device__ __forceinline__ unsigned short bhi(float x) {
    union { bf16 b; unsigned short u; } cv; cv.b = __float2bfloat16(x); return cv.u;
}
__device__ __forceinline__ unsigned short blo(float x, unsigned short h) {
    float hf = __uint_as_float(((unsigned int)h) << 16);
    union { bf16 b; unsigned short u; } cv; cv.b = __float2bfloat16(x - hf); return cv.u;
}

__device__ __forceinline__ void storeC(float* p, float v) { *p = v; }
__device__ __forceinline__ void storeC(bf16* p, float v) { *p = __float2bfloat16(v); }

// async global->LDS, 16B per lane; lds dest = wave-uniform base + lane*16
__device__ __forceinline__ void gload_lds16(const bf16* g, bf16* l) {
    __builtin_amdgcn_global_load_lds(
        (const __attribute__((address_space(1))) void*)g,
        (__attribute__((address_space(3))) void*)l,
        16, 0, 0);
}

// ---------------- K1: mid = x @ lora_a^T  (NT x 8), fp32 in ----------------
__global__ __launch_bounds__(256) void lora_mid_kernel(const float* __restrict__ x,
        const float* __restrict__ la, float* __restrict__ mid) {
    int t = blockIdx.x * 4 + (threadIdx.x >> 6);
    int lane = threadIdx.x & 63;
    if (t >= NT) return;
    float acc[8];
#pragma unroll
    for (int r = 0; r < 8; r++) acc[r] = 0.f;
    const float* xr = x + (size_t)t * EDIM;
    for (int e = lane; e < EDIM; e += 64) {
        float xv = xr[e];
#pragma unroll
        for (int r = 0; r < 8; r++) acc[r] += xv * la[r * EDIM + e];
    }
#pragma unroll
    for (int r = 0; r < 8; r++) {
        float v = acc[r];
#pragma unroll
        for (int off = 32; off >= 1; off >>= 1) v += __shfl_xor(v, off, 64);
        if (lane == 0) mid[(size_t)t * 8 + r] = v;
    }
}

// ---- split fp32 rows x 768 -> bf16 [hi | lo] rows x 1536 (used for W and for x) --------
__global__ __launch_bounds__(256) void split_w_kernel(const float* __restrict__ w,
        bf16* __restrict__ o, int rows) {
    int idx = blockIdx.x * 256 + threadIdx.x;
    int total = rows * 192;                        // 768/4 float4-chunks per row
    if (idx >= total) return;
    int r = idx / 192, c = (idx - r * 192) * 4;
    float4 v = *reinterpret_cast<const float4*>(w + (size_t)r * 768 + c);
    ushort4 hi, lo;
    hi.x = bhi(v.x); hi.y = bhi(v.y); hi.z = bhi(v.z); hi.w = bhi(v.w);
    lo.x = blo(v.x, hi.x); lo.y = blo(v.y, hi.y); lo.z = blo(v.z, hi.z); lo.w = blo(v.w, hi.w);
    *(ushort4*)(o + (size_t)r * 1536 + c) = hi;
    *(ushort4*)(o + (size_t)r * 1536 + 768 + c) = lo;
}

// ---------------- MFMA GEMM, 256x256 tile, fine-interleaved counted-vmcnt pipeline ------
// (round-7 version, best measured: QKV 563 us, MfmaUtil 31%. The r8 per-phase
// barrier variant regressed to 621 — 7 barriers/tile cost more than role-split
// gains at 16-MFMA phase size. Keeping the barrier-free cluster schedule.)
// Virtual-K decomposition (fp32 accuracy from bf16 MFMA):
//   QKV  (KV=2304, A = xs [x_hi | x_lo], lda=1536): x_hi@Whi + x_hi@Wlo + x_lo@Whi
//   proj (KV=1536, A = ao,               lda=768 ): ao@Whi + ao@Wlo
// 8 waves (2M x 4N), per-wave output 128x64, BK=64; LDS = 128 KiB (2x dbuf).
//   A: read a(mh0)+b0; 16 MFMA   B: read b1; 16 MFMA   C: read a(mh1); 16 MFMA
//   bar1 | STAGE t+2 into freed buf | sched_barrier | D: 16 MFMA (regs only)
//   vmcnt(8) counted | bar2 | cur^=1
template <typename OT, bool LORA>
__global__ __launch_bounds__(512, 2) void mfma_gemm_kernel(const bf16* __restrict__ A, int lda,
        const bf16* __restrict__ W, const float* __restrict__ bias,
        const float* __restrict__ mid, const float* __restrict__ lb,
        OT* __restrict__ C, int M, int N, int KV) {
    __shared__ bf16 As[2][256 * 64];
    __shared__ bf16 Bs[2][256 * 64];
    const int tid = threadIdx.x;
    const int w = tid >> 6, lane = tid & 63;
    const int lr = lane & 15, lg = lane >> 4;
    const int wr = w >> 2, wc = w & 3;          // 2M x 4N wave grid

    // bijective XCD-chunk swizzle (general form, m204)
    const int gx = gridDim.x;
    const int nwg = gx * gridDim.y;
    const int flat = blockIdx.y * gx + blockIdx.x;
    const int xcd = flat & 7, loc = flat >> 3;
    const int q = nwg >> 3, rmd = nwg & 7;
    const int lid = (xcd < rmd ? xcd * (q + 1) : rmd * (q + 1) + (xcd - rmd) * q) + loc;
    const int m0 = (lid / gx) * 256, n0 = (lid % gx) * 256;

    f32x4 acc[8][4];
#pragma unroll
    for (int i = 0; i < 8; i++)
#pragma unroll
        for (int j = 0; j < 4; j++) acc[i][j] = (f32x4){0.f, 0.f, 0.f, 0.f};

    // staging source swizzle (rule #21)
    const int brs = lane >> 3;
    const int bcsw = ((lane & 7) ^ brs) << 3;

    auto STAGE = [&](bf16* dA, bf16* dB, int aO, int wO) {
#pragma unroll
        for (int j = 0; j < 4; ++j) {
            int rA = w * 32 + j * 8;
            gload_lds16(A + (size_t)(m0 + rA + brs) * lda + aO + bcsw, dA + rA * 64);
            gload_lds16(W + (size_t)(n0 + rA + brs) * 1536 + wO + bcsw, dB + rA * 64);
        }
    };

    const int nt = KV / 64;
    STAGE(&As[0][0], &Bs[0][0], 0, 0);
    {
        const int k1 = 64;
        STAGE(&As[1][0], &Bs[1][0], (k1 >= 768) ? k1 - 768 : k1, k1);
    }
    asm volatile("s_waitcnt vmcnt(8)" ::: "memory");
    __builtin_amdgcn_sched_barrier(0);
    __builtin_amdgcn_s_barrier();
    __builtin_amdgcn_sched_barrier(0);

    int cur = 0;
    for (int t = 0; t < nt; ++t) {
        const char* pA = (const char*)&As[cur][0];
        const char* pB = (const char*)&Bs[cur][0];
        bf16x8 a[4][2], b0[2][2], b1[2][2];
        // ---- cluster A: a(m-half0) + b0 ----
#pragma unroll
        for (int mf = 0; mf < 4; mf++) {
            int row = wr * 128 + mf * 16 + lr;
            int sw = (row & 7) << 4;
            a[mf][0] = *(const bf16x8*)(pA + row * 128 + ((lg * 16) ^ sw));
            a[mf][1] = *(const bf16x8*)(pA + row * 128 + ((64 + lg * 16) ^ sw));
        }
#pragma unroll
        for (int nf = 0; nf < 2; nf++) {
            int row = wc * 64 + nf * 16 + lr;
            int sw = (row & 7) << 4;
            b0[nf][0] = *(const bf16x8*)(pB + row * 128 + ((lg * 16) ^ sw));
            b0[nf][1] = *(const bf16x8*)(pB + row * 128 + ((64 + lg * 16) ^ sw));
        }
        __builtin_amdgcn_s_setprio(1);
#pragma unroll
        for (int mf = 0; mf < 4; mf++)
#pragma unroll
            for (int nf = 0; nf < 2; nf++) {
                acc[mf][nf] = __builtin_amdgcn_mfma_f32_16x16x32_bf16(a[mf][0], b0[nf][0], acc[mf][nf], 0, 0, 0);
                acc[mf][nf] = __builtin_amdgcn_mfma_f32_16x16x32_bf16(a[mf][1], b0[nf][1], acc[mf][nf], 0, 0, 0);
            }
        __builtin_amdgcn_s_setprio(0);
        // ---- cluster B: b1; a * b1 ----
#pragma unroll
        for (int nf = 0; nf < 2; nf++) {
            int row = wc * 64 + (nf + 2) * 16 + lr;
            int sw = (row & 7) << 4;
            b1[nf][0] = *(const bf16x8*)(pB + row * 128 + ((lg * 16) ^ sw));
            b1[nf][1] = *(const bf16x8*)(pB + row * 128 + ((64 + lg * 16) ^ sw));
        }
        __builtin_amdgcn_s_setprio(1);
#pragma unroll
        for (int mf = 0; mf < 4; mf++)
#pragma unroll
            for (int nf = 0; nf < 2; nf++) {
                acc[mf][nf + 2] = __builtin_amdgcn_mfma_f32_16x16x32_bf16(a[mf][0], b1[nf][0], acc[mf][nf + 2], 0, 0, 0);
                acc[mf][nf + 2] = __builtin_amdgcn_mfma_f32_16x16x32_bf16(a[mf][1], b1[nf][1], acc[mf][nf + 2], 0, 0, 0);
            }
        __builtin_amdgcn_s_setprio(0);
        // ---- cluster C: overwrite a with m-half1 (WAR orders vs B); a * b1 ----
#pragma unroll
        for (int mf = 0; mf < 4; mf++) {
            int row = wr * 128 + 64 + mf * 16 + lr;
            int sw = (row & 7) << 4;
            a[mf][0] = *(const bf16x8*)(pA + row * 128 + ((lg * 16) ^ sw));
            a[mf][1] = *(const bf16x8*)(pA + row * 128 + ((64 + lg * 16) ^ sw));
        }
        __builtin_amdgcn_s_setprio(1);
#pragma unroll
        for (int mf = 0; mf < 4; mf++)
#pragma unroll
            for (int nf = 0; nf < 2; nf++) {
                acc[4 + mf][nf + 2] = __builtin_amdgcn_mfma_f32_16x16x32_bf16(a[mf][0], b1[nf][0], acc[4 + mf][nf + 2], 0, 0, 0);
                acc[4 + mf][nf + 2] = __builtin_amdgcn_mfma_f32_16x16x32_bf16(a[mf][1], b1[nf][1], acc[4 + mf][nf + 2], 0, 0, 0);
            }
        __builtin_amdgcn_s_setprio(0);
        // ---- bar1: buf[cur] dead for all waves ----
        __builtin_amdgcn_sched_barrier(0);
        __builtin_amdgcn_s_barrier();
        __builtin_amdgcn_sched_barrier(0);
        // ---- stage tile t+2 into the freed buffer (overlaps cluster D) ----
        if (t + 2 < nt) {
            const int k2 = (t + 2) * 64;
            STAGE(&As[cur][0], &Bs[cur][0],
                  (k2 >= 768) ? k2 - 768 : k2,
                  (k2 >= 1536) ? k2 - 1536 : k2);
        }
        __builtin_amdgcn_sched_barrier(0);   // keep D's MFMAs after the stage issue
        // ---- cluster D: a(m-half1) * b0 — registers only ----
        __builtin_amdgcn_s_setprio(1);
#pragma unroll
        for (int mf = 0; mf < 4; mf++)
#pragma unroll
            for (int nf = 0; nf < 2; nf++) {
                acc[4 + mf][nf] = __builtin_amdgcn_mfma_f32_16x16x32_bf16(a[mf][0], b0[nf][0], acc[4 + mf][nf], 0, 0, 0);
                acc[4 + mf][nf] = __builtin_amdgcn_mfma_f32_16x16x32_bf16(a[mf][1], b0[nf][1], acc[4 + mf][nf], 0, 0, 0);
            }
        __builtin_amdgcn_s_setprio(0);
        // ---- counted wait for tile t+1 (t+2's 8 loads stay in flight) ----
        if (t + 2 < nt) {
            asm volatile("s_waitcnt vmcnt(8)" ::: "memory");
        } else {
            asm volatile("s_waitcnt vmcnt(0)" ::: "memory");
        }
        __builtin_amdgcn_sched_barrier(0);
        __builtin_amdgcn_s_barrier();            // t+1's LDS writes visible to all
        __builtin_amdgcn_sched_barrier(0);
        cur ^= 1;
    }
    // ---- epilogue: bias (+ LoRA), store ----
#pragma unroll
    for (int mf = 0; mf < 8; mf++) {
#pragma unroll
        for (int r = 0; r < 4; r++) {
            int m = m0 + wr * 128 + mf * 16 + lg * 4 + r;
            if (m < M) {
                float mr[8];
                if constexpr (LORA) {
                    float4 u0 = *reinterpret_cast<const float4*>(mid + (size_t)m * 8);
                    float4 u1 = *reinterpret_cast<const float4*>(mid + (size_t)m * 8 + 4);
                    mr[0] = u0.x; mr[1] = u0.y; mr[2] = u0.z; mr[3] = u0.w;
                    mr[4] = u1.x; mr[5] = u1.y; mr[6] = u1.z; mr[7] = u1.w;
                }
#pragma unroll
                for (int nf = 0; nf < 4; nf++) {
                    int n = n0 + wc * 64 + nf * 16 + lr;
                    float v = acc[mf][nf][r] + bias[n];
                    if constexpr (LORA) {
                        const float4 l0 = *reinterpret_cast<const float4*>(lb + (size_t)n * 8);
                        const float4 l1 = *reinterpret_cast<const float4*>(lb + (size_t)n * 8 + 4);
                        v += mr[0] * l0.x + mr[1] * l0.y + mr[2] * l0.z + mr[3] * l0.w
                           + mr[4] * l1.x + mr[5] * l1.y + mr[6] * l1.z + mr[7] * l1.w;
                    }
                    storeC(C + (size_t)m * N + n, v);
                }
            }
        }
    }
}

// ---------------- Fused per-frame attention, MFMA version ----------------
// r9: Q A-frags for ALL owned q-tiles hoisted BEFORE staging (overlaps the K/V
// staging + barrier; removes 2 serial ~500cyc global loads from each tile's
// critical path). qa[] statically indexed via full unroll (rule #20).
__global__ __launch_bounds__(256) void attn_kernel(const bf16* __restrict__ qkv,
        bf16* __restrict__ ao) {
    __shared__ bf16 Ks[208 * 64];      // [row][64]
    __shared__ bf16 Vt[64 * 208];      // [d][kk]
    __shared__ bf16 Ps[4][16 * 208];   // per-wave [q][kk]
    const int bb = blockIdx.x / NH;
    const int h = blockIdx.x % NH;
    const bf16* base = qkv + (size_t)bb * TP * N3;
    const int tid = threadIdx.x;
    const int w = tid >> 6, lane = tid & 63;
    const int lr = lane & 15, lg = lane >> 4;

    // ---- hoisted Q loads (issue before staging; consumed after barrier) ----
    bf16x8 qa[4][2];
#pragma unroll
    for (int ti = 0; ti < 4; ti++) {
        int qt = w + ti * 4;
        if (qt < 13) {
            int q = qt * 16 + lr; if (q > TP - 1) q = TP - 1;
            const bf16* qp = base + (size_t)q * N3 + h * 64 + lg * 8;
            qa[ti][0] = *(const bf16x8*)qp;
            qa[ti][1] = *(const bf16x8*)(qp + 32);
        }
    }

    for (int idx = tid; idx < 208 * 16; idx += 256) {
        int row = idx >> 4, d4 = (idx & 15) * 4;
        ushort4 v = make_ushort4(0, 0, 0, 0);
        if (row < TP)
            v = *(const ushort4*)(base + (size_t)row * N3 + EDIM + h * 64 + d4);
        *(ushort4*)((char*)Ks + ((row * 128 + d4 * 2) ^ ((row & 7) << 4))) = v;
    }
    for (int g = w; g < 52; g += 4) {
        int kk0 = g * 4;
        int d = lane;
        const bf16* vb = base + (size_t)kk0 * N3 + 2 * EDIM + h * 64 + d;
        unsigned short t0 = 0, t1 = 0, t2 = 0, t3 = 0;
        if (kk0 + 0 < TP) t0 = *(const unsigned short*)(vb);
        if (kk0 + 1 < TP) t1 = *(const unsigned short*)(vb + N3);
        if (kk0 + 2 < TP) t2 = *(const unsigned short*)(vb + 2 * N3);
        if (kk0 + 3 < TP) t3 = *(const unsigned short*)(vb + 3 * N3);
        ushort4 v; v.x = t0; v.y = t1; v.z = t2; v.w = t3;
        *(ushort4*)((char*)Vt + ((d * 416 + kk0 * 2) ^ ((d & 7) << 4))) = v;
    }
    __syncthreads();

    bf16* Pw = &Ps[w][0];

#pragma unroll
    for (int ti = 0; ti < 4; ti++) {
        int qt = w + ti * 4;
        if (qt >= 13) continue;

        f32x4 sf[13];
#pragma unroll
        for (int f = 0; f < 13; f++) {
            int row = f * 16 + lr;
            int swz = (row & 7) << 4;
            bf16x8 kb0 = *(const bf16x8*)((const char*)Ks + ((row * 128 + lg * 16) ^ swz));
            bf16x8 kb1 = *(const bf16x8*)((const char*)Ks + ((row * 128 + 64 + lg * 16) ^ swz));
            f32x4 c = {0.f, 0.f, 0.f, 0.f};
            c = __builtin_amdgcn_mfma_f32_16x16x32_bf16(qa[ti][0], kb0, c, 0, 0, 0);
            c = __builtin_amdgcn_mfma_f32_16x16x32_bf16(qa[ti][1], kb1, c, 0, 0, 0);
            sf[f] = c;
        }

        float mx[4] = {-1e30f, -1e30f, -1e30f, -1e30f};
#pragma unroll
        for (int f = 0; f < 13; f++) {
#pragma unroll
            for (int r = 0; r < 4; r++) {
                float s = sf[f][r] * SCALE;
                if (f == 12 && lr >= 5) s = -1e30f;
                sf[f][r] = s;
                mx[r] = fmaxf(mx[r], s);
            }
        }
#pragma unroll
        for (int off = 8; off >= 1; off >>= 1) {
#pragma unroll
            for (int r = 0; r < 4; r++) mx[r] = fmaxf(mx[r], __shfl_xor(mx[r], off, 64));
        }
        float lsum[4] = {0.f, 0.f, 0.f, 0.f};
#pragma unroll
        for (int f = 0; f < 13; f++) {
#pragma unroll
            for (int r = 0; r < 4; r++) {
                float e = __expf(sf[f][r] - mx[r]);
                sf[f][r] = e;
                lsum[r] += e;
            }
        }
#pragma unroll
        for (int off = 8; off >= 1; off >>= 1) {
#pragma unroll
            for (int r = 0; r < 4; r++) lsum[r] += __shfl_xor(lsum[r], off, 64);
        }
        float inv[4];
#pragma unroll
        for (int r = 0; r < 4; r++) inv[r] = 1.f / lsum[r];

#pragma unroll
        for (int f = 0; f < 13; f++) {
#pragma unroll
            for (int r = 0; r < 4; r++) {
                int row = lg * 4 + r;
                int col = f * 16 + lr;
                *(bf16*)((char*)Pw + ((row * 416 + col * 2) ^ ((row & 7) << 4))) =
                    __float2bfloat16(sf[f][r]);
            }
        }

        f32x4 of[4];
#pragma unroll
        for (int dt = 0; dt < 4; dt++) of[dt] = (f32x4){0.f, 0.f, 0.f, 0.f};
#pragma unroll
        for (int ks = 0; ks < 7; ks++) {
            int k0 = ks * 32 + lg * 8;
            bool ok = (k0 < 208);
            bf16x8 pa = {0, 0, 0, 0, 0, 0, 0, 0};
            if (ok)
                pa = *(const bf16x8*)((const char*)Pw + ((lr * 416 + k0 * 2) ^ ((lr & 7) << 4)));
#pragma unroll
            for (int dt = 0; dt < 4; dt++) {
                bf16x8 vb = {0, 0, 0, 0, 0, 0, 0, 0};
                if (ok) {
                    int d = dt * 16 + lr;
                    vb = *(const bf16x8*)((const char*)Vt + ((d * 416 + k0 * 2) ^ ((d & 7) << 4)));
                }
                of[dt] = __builtin_amdgcn_mfma_f32_16x16x32_bf16(pa, vb, of[dt], 0, 0, 0);
            }
        }

#pragma unroll
        for (int dt = 0; dt < 4; dt++) {
#pragma unroll
            for (int r = 0; r < 4; r++) {
                int qq = qt * 16 + lg * 4 + r;
                if (qq < TP)
                    ao[((size_t)bb * TP + qq) * EDIM + h * 64 + dt * 16 + lr] =
                        __float2bfloat16(of[dt][r] * inv[r]);
            }
        }
    }
}

// ------- Cross-frame CLS attention, KV-split x4 (flash partials + merge) ---------------
// r9: old xattn had 192 blocks on 256 CUs (0.75 blocks/CU — occupancy bug).
// Split the KALL=2364 key axis into NCH=4 chunks of 591 -> 768 blocks; each
// writes unnormalized O_c plus (m_c, l_c); tiny merge kernel combines:
//   M = max m_c; L = sum l_c e^{m_c-M}; O = sum O_c e^{m_c-M}; x1 = O/L.
__global__ __launch_bounds__(256) void xattn_part_kernel(const bf16* __restrict__ qkv,
        float* __restrict__ Opart, float* __restrict__ mlp) {
    __shared__ float q1[NF][64];
    __shared__ bf16 Ks[128][64];
    __shared__ bf16 Vs[128][64];
    __shared__ float sc[NF][128];
    __shared__ float Oacc[NF][64];
    __shared__ float mrow[NF], lrow[NF], arow[NF];
    const int bid = blockIdx.x;
    const int c = bid & (NCH - 1);
    const int bh = bid >> 2;
    const int b = bh / NH, h = bh % NH;
    const int tid = threadIdx.x;
    const int kbeg = c * KCH, kend = kbeg + KCH;
    for (int idx = tid; idx < NF * 64; idx += 256) {
        int f = idx >> 6, d = idx & 63;
        q1[f][d] = b2f(qkv[(size_t)((b * NF + f) * TP) * N3 + h * 64 + d]);
        Oacc[f][d] = 0.f;
    }
    if (tid < NF) { mrow[tid] = -1e30f; lrow[tid] = 0.f; }
    __syncthreads();
    const int w = tid >> 6, lane = tid & 63;
    for (int kk0 = kbeg; kk0 < kend; kk0 += 128) {
        for (int idx = tid; idx < 128 * 16; idx += 256) {
            int r = idx >> 4, d4 = (idx & 15) * 4;
            int kk = kk0 + r;
            if (kk < kend) {
                int f = kk / TP, pp = kk - f * TP;
                const bf16* src = qkv + (size_t)((b * NF + f) * TP + pp) * N3 + h * 64 + d4;
                *(ushort4*)&Ks[r][d4] = *(const ushort4*)(src + 768);
                *(ushort4*)&Vs[r][d4] = *(const ushort4*)(src + 1536);
            } else {
                ushort4 z; z.x = z.y = z.z = z.w = 0;
                *(ushort4*)&Ks[r][d4] = z;
                *(ushort4*)&Vs[r][d4] = z;
            }
        }
        __syncthreads();
        for (int idx = tid; idx < NF * 128; idx += 256) {
            int f = idx >> 7, r = idx & 127;
            float s = -1e30f;
            if (kk0 + r < kend) {
                const bf16* kr = &Ks[r][0];
                float a = 0.f;
#pragma unroll
                for (int d2 = 0; d2 < 32; d2++) {
                    unsigned int u = *reinterpret_cast<const unsigned int*>(kr + 2 * d2);
                    a += q1[f][2 * d2] * __uint_as_float(u << 16);
                    a += q1[f][2 * d2 + 1] * __uint_as_float(u & 0xffff0000u);
                }
                s = a * SCALE;
            }
            sc[f][r] = s;
        }
        __syncthreads();
        for (int qi = 0; qi < 3; qi++) {
            int f = qi * 4 + w;
            float s0 = sc[f][lane], s1v = sc[f][lane + 64];
            float mx = fmaxf(s0, s1v);
#pragma unroll
            for (int off = 32; off >= 1; off >>= 1) mx = fmaxf(mx, __shfl_xor(mx, off, 64));
            float mold = mrow[f];
            float mnew = fmaxf(mold, mx);
            float e0 = __expf(s0 - mnew), e1 = __expf(s1v - mnew);
            float ls = e0 + e1;
#pragma unroll
            for (int off = 32; off >= 1; off >>= 1) ls += __shfl_xor(ls, off, 64);
            sc[f][lane] = e0; sc[f][lane + 64] = e1;
            if (lane == 0) {
                float alpha = __expf(mold - mnew);
                arow[f] = alpha;
                lrow[f] = lrow[f] * alpha + ls;
                mrow[f] = mnew;
            }
        }
        __syncthreads();
        for (int idx = tid; idx < NF * 64; idx += 256) {
            int f = idx >> 6, d = idx & 63;
            float o = Oacc[f][d] * arow[f];
#pragma unroll 4
            for (int r = 0; r < 128; r++)
                o += sc[f][r] * b2f(Vs[r][d]);
            Oacc[f][d] = o;
        }
        __syncthreads();
    }
    // ---- write unnormalized partials ----
    for (int idx = tid; idx < NF * 64; idx += 256) {
        int f = idx >> 6, d = idx & 63;
        Opart[((size_t)bid * NF + f) * 64 + d] = Oacc[f][d];
    }
    if (tid < NF) {
        mlp[(size_t)bid * NF * 2 + tid] = mrow[tid];
        mlp[(size_t)bid * NF * 2 + NF + tid] = lrow[tid];
    }
}

__global__ __launch_bounds__(256) void xattn_merge_kernel(const float* __restrict__ Opart,
        const float* __restrict__ mlp, float* __restrict__ x1p) {
    const int bh = blockIdx.x;
    const int b = bh / NH, h = bh % NH;
    const int tid = threadIdx.x;
    for (int idx = tid; idx < NF * 64; idx += 256) {
        int f = idx >> 6, d = idx & 63;
        float M = -1e30f;
#pragma unroll
        for (int c = 0; c < NCH; c++)
            M = fmaxf(M, mlp[(size_t)(bh * NCH + c) * NF * 2 + f]);
        float L = 0.f, O = 0.f;
#pragma unroll
        for (int c = 0; c < NCH; c++) {
            int pb = bh * NCH + c;
            float s = __expf(mlp[(size_t)pb * NF * 2 + f] - M);
            L += mlp[(size_t)pb * NF * 2 + NF + f] * s;
            O += Opart[((size_t)pb * NF + f) * 64 + d] * s;
        }
        x1p[(size_t)(b * NF + f) * EDIM + h * 64 + d] = O / L;
    }
}

// ---------------- CLS fixup: out[:,:,0,:] = MLP(out[:,:,0,:]) + x1p @ Wout^T + ob --------
__global__ __launch_bounds__(256) void cls_kernel(float* __restrict__ out,
        const float* __restrict__ x1p, const float* __restrict__ Wout, const float* __restrict__ ob,
        const float* __restrict__ dw, const float* __restrict__ db,
        const float* __restrict__ uw, const float* __restrict__ ub) {
    __shared__ float x0s[EDIM], x1s[EDIM], gs[8];
    const int bfi = blockIdx.x;
    float* row = out + (size_t)bfi * TP * EDIM;  // p = 0 row
    const int tid = threadIdx.x;
    for (int i = tid; i < EDIM; i += 256) {
        x0s[i] = row[i];
        x1s[i] = x1p[(size_t)bfi * EDIM + i];
    }
    __syncthreads();
    {
        int r = tid >> 5, sl = tid & 31;
        float pr = 0.f;
        for (int e = sl; e < EDIM; e += 32) pr += x0s[e] * dw[r * EDIM + e];
#pragma unroll
        for (int off = 16; off >= 1; off >>= 1) pr += __shfl_xor(pr, off, 64);
        if (sl == 0) gs[r] = pr + db[r];
    }
    __syncthreads();
    float act[8];
#pragma unroll
    for (int r = 0; r < 8; r++) { float g = gs[r]; act[r] = g / (1.f + __expf(-1.702f * g)); }
    for (int j = tid; j < EDIM; j += 256) {
        float y = ub[j] + ob[j];
        const float4 u0 = *reinterpret_cast<const float4*>(uw + (size_t)j * 8);
        const float4 u1 = *reinterpret_cast<const float4*>(uw + (size_t)j * 8 + 4);
        y += act[0] * u0.x + act[1] * u0.y + act[2] * u0.z + act[3] * u0.w
           + act[4] * u1.x + act[5] * u1.y + act[6] * u1.z + act[7] * u1.w;
        const float* wr = Wout + (size_t)j * EDIM;
        float s = 0.f;
        for (int e = 0; e < EDIM; e += 4) {
            float4 wv = *reinterpret_cast<const float4*>(wr + e);
            s += x1s[e] * wv.x + x1s[e + 1] * wv.y + x1s[e + 2] * wv.z + x1s[e + 3] * wv.w;
        }
        y += s;
        row[j] = y;
    }
}

extern "C" void kernel_launch(void* const* d_in, const int* in_sizes, int n_in,
                              void* d_out, int out_size, void* d_ws, size_t ws_size,
                              hipStream_t stream) {
    (void)in_sizes; (void)n_in; (void)out_size; (void)ws_size;
    const float* x   = (const float*)d_in[0];
    const float* ipw = (const float*)d_in[1];
    const float* ipb = (const float*)d_in[2];
    const float* opw = (const float*)d_in[3];
    const float* opb = (const float*)d_in[4];
    const float* la  = (const float*)d_in[5];
    const float* lb  = (const float*)d_in[6];
    const float* dw  = (const float*)d_in[7];
    const float* db  = (const float*)d_in[8];
    const float* uw  = (const float*)d_in[9];
    const float* ub  = (const float*)d_in[10];
    float* out = (float*)d_out;   // fp32 output per reference dtype

    // workspace: qkv 174.3 + ao 58.2 + xs 116.4 + W1 7.1 + W2 2.4 + mid 1.2 + x1p 0.6
    //            + Opart 2.4 + mlp 0.07  ≈ 363 MB
    char* wsb = (char*)d_ws;
    bf16* qkv = (bf16*)wsb;                       wsb += (size_t)NT * N3 * sizeof(bf16);
    bf16* ao  = (bf16*)wsb;                       wsb += (size_t)MPAD * EDIM * sizeof(bf16);
    bf16* xs  = (bf16*)wsb;                       wsb += (size_t)MPAD * 1536 * sizeof(bf16);
    bf16* W1  = (bf16*)wsb;                       wsb += (size_t)N3 * 1536 * sizeof(bf16);
    bf16* W2  = (bf16*)wsb;                       wsb += (size_t)EDIM * 1536 * sizeof(bf16);
    float* mid = (float*)wsb;                     wsb += (size_t)NT * 8 * sizeof(float);
    float* x1p = (float*)wsb;                     wsb += (size_t)NB * NF * EDIM * sizeof(float);
    float* Opart = (float*)wsb;                   wsb += (size_t)NB * NH * NCH * NF * 64 * sizeof(float);
    float* mlp = (float*)wsb;                     wsb += (size_t)NB * NH * NCH * NF * 2 * sizeof(float);

    split_w_kernel<<<(N3 * 192 + 255) / 256, 256, 0, stream>>>(ipw, W1, N3);
    split_w_kernel<<<(EDIM * 192 + 255) / 256, 256, 0, stream>>>(opw, W2, EDIM);
    split_w_kernel<<<(NT * 192 + 255) / 256, 256, 0, stream>>>(x, xs, NT);
    lora_mid_kernel<<<NT / 4, 256, 0, stream>>>(x, la, mid);
    // QKV: virtual K = 2304 (hi*Whi + hi*Wlo + lo*Whi)
    mfma_gemm_kernel<bf16, true><<<dim3(N3 / 256, MPAD / 256), 512, 0, stream>>>(
        xs, 1536, W1, ipb, mid, lb, qkv, NT, N3, 2304);
    attn_kernel<<<192 * NH, 256, 0, stream>>>(qkv, ao);
    xattn_part_kernel<<<NB * NH * NCH, 256, 0, stream>>>(qkv, Opart, mlp);
    xattn_merge_kernel<<<NB * NH, 256, 0, stream>>>(Opart, mlp, x1p);
    // out-proj: virtual K = 1536 (ao*Whi + ao*Wlo)
    mfma_gemm_kernel<float, false><<<dim3(EDIM / 256, MPAD / 256), 512, 0, stream>>>(
        ao, 768, W2, opb, nullptr, nullptr, out, NT, EDIM, 1536);
    cls_kernel<<<NB * NF, 256, 0, stream>>>(out, x1p, opw, opb, dw, db, uw, ub);
}